// Round 13
// baseline (313.232 us; speedup 1.0000x reference)
//
#include <hip/hip_runtime.h>
#include <hip/hip_bf16.h>
#include <math.h>

// Problem constants
static constexpr int kB = 256;
static constexpr int kL = 256;
static constexpr int kD = 100;
static constexpr int kLIN = 512;
static constexpr int SZ_E = kB * kL * kD;     // 6,553,600
static constexpr int W_FRAG = 7 * 8 * 64 * 8; // 28672 bf16 per layer

typedef short  s8_t  __attribute__((ext_vector_type(8)));
typedef float  f4_t  __attribute__((ext_vector_type(4)));

// sbf fragment storage (hi-only bf16): rowgroup g = row>>4, slot s in [0,4):
//   ((size_t)g*4 + s)*512 shorts, lane = quad*16 + (row&15), 8 shorts/lane,
//   k = s*32 + quad*8 + j (identity). sq from the SAME bf16-rounded values.
// W fragments pi-permuted (wprep); matchf's Dp registers feed the f-GEMM MFMA.
// matchf CLOSED at r19 (41.3us): stage+XCD-grid; monolith/no-LDS/gload_lds/
// batching+setprio all worse (r16-r23). NEVER use __launch_bounds__(256,4)
// on >=100-VGPR kernels (caps VGPR at 64 -> scratch spills, r20).
// conv r24: 32-row tiles. r25: match_sums jt-merge (w1 plain store) + head
// k-split (total 315.7->306.2).
// r26 (RESUBMIT after infra failure -- "container failed twice" at acquire,
// no kernel verdict): embprep + poolprep to 32-row tiles (same mechanism as
// conv r24): halo/barrier/atomic-tail amortized 2x; sq_store/frag_store
// called twice with row-offset pointers. embprep 2048 blocks (xcat atomics
// halved); poolprep halo 34/32 rows, 27.7KB LDS.

__device__ __forceinline__ unsigned short f2bf(float x) {
    __hip_bfloat16 h = __float2bfloat16(x);
    return *(unsigned short*)&h;
}
__device__ __forceinline__ float bf2f(unsigned short u) {
    unsigned int w = ((unsigned int)u) << 16;
    return *(float*)&w;
}
__device__ __forceinline__ float ftanh(float x) {
    // tanh(|x|) = (1 - e^{-2|x|}) / (1 + e^{-2|x|}); rcp instead of IEEE div.
    float ax = fabsf(x);
    float t = __expf(-2.f * ax);
    float r = (1.f - t) * __builtin_amdgcn_rcpf(1.f + t);
    return copysignf(r, x);
}

// write one rowgroup (16 rows in rb[16][104]) as 4 coalesced hi fragments (one per wave)
__device__ __forceinline__ void frag_store(const float (*rb)[104], const float* vsh,
                                           unsigned short* sb, int g, int tid) {
    int lane = tid & 63, wave = tid >> 6;   // wave = slot
    int qd = (lane >> 4) & 3, r15 = lane & 15;
    float v = vsh[r15];
    int kbase = wave * 32 + qd * 8;
    s8_t stv;
#pragma unroll
    for (int j = 0; j < 8; ++j) {
        int k = kbase + j;
        float x = (k < kD) ? rb[r15][k] * v : 0.f;
        stv[j] = (short)f2bf(x);
    }
    *(s8_t*)(sb + ((size_t)g * 4 + wave) * 512 + lane * 8) = stv;
}

// per-row sum of squares of bf16-ROUNDED masked values (16 threads/row)
__device__ __forceinline__ void sq_store(const float (*rb)[104], const float* vsh,
                                         float* sq, int row0, int tid) {
    int r = tid >> 4, j = tid & 15;
    float v = vsh[r];
    float s = 0.f;
    for (int d = j; d < kD; d += 16) { float x = bf2f(f2bf(rb[r][d] * v)); s += x * x; }
#pragma unroll
    for (int m = 8; m >= 1; m >>= 1) s += __shfl_xor(s, m, 64);
    if (j == 0) sq[row0 + r] = s;
}

// ------------------------------------------------------------- embed + prep + fused mean
// r26: 32-row tiles (2048 blocks/side; xcat atomic passes halved).
__global__ __launch_bounds__(256) void embprep_kernel(const int* __restrict__ q1,
                                                      const int* __restrict__ q2,
                                                      const float* __restrict__ emb,
                                                      float* __restrict__ e1,
                                                      float* __restrict__ e2,
                                                      unsigned short* __restrict__ sbf1,
                                                      unsigned short* __restrict__ sbf2,
                                                      float* __restrict__ sq1,
                                                      float* __restrict__ sq2,
                                                      float* __restrict__ xcat) {
    __shared__ float rb[32][104];
    __shared__ float vsh[32];
    int side = blockIdx.y;
    const int* q = side ? q2 : q1;
    float* e = side ? e2 : e1;
    unsigned short* sb = side ? sbf2 : sbf1;
    float* sq = side ? sq2 : sq1;
    int tid = threadIdx.x;
    int row0 = blockIdx.x * 32;
    int b = row0 >> 8;
    if (tid < 32) vsh[tid] = (q[row0 + tid] != 0) ? 1.f : 0.f;
    for (int t = tid; t < 800; t += 256) {
        int r = t / 25, c = t - r * 25;
        int qv = q[row0 + r];
        float4 v4 = *(const float4*)(emb + (size_t)qv * kD + c * 4);
        *(float4*)(e + (size_t)(row0 + r) * kD + c * 4) = v4;
        *(float4*)&rb[r][c * 4] = v4;
    }
    __syncthreads();
    sq_store(rb, vsh, sq, row0, tid);
    sq_store(rb + 16, vsh + 16, sq, row0 + 16, tid);
    if (tid < kD) {
        float s = 0.f;
#pragma unroll
        for (int r = 0; r < 32; ++r) s += rb[r][tid];
        atomicAdd(&xcat[b * 600 + side * 300 + tid], s * (1.0f / kL));
    }
    frag_store(rb, vsh, sb, row0 >> 4, tid);
    frag_store(rb + 16, vsh + 16, sb, (row0 >> 4) + 1, tid);
}

// ------------------------------------------------------------- fused match + f-GEMM
// r19 FINAL: r15 body; grid (b, side, itile) so all 4 blocks of a b share one XCD L2.
__global__ __launch_bounds__(256) void matchf_kernel(const unsigned short* __restrict__ sbf1,
                                                     const unsigned short* __restrict__ sbf2,
                                                     const float* __restrict__ sq1,
                                                     const float* __restrict__ sq2,
                                                     const unsigned short* __restrict__ Wf,
                                                     unsigned short* __restrict__ f1,
                                                     unsigned short* __restrict__ f2) {
    __shared__ short lb[8 * 4 * 512];   // 32KB: contraction-side fragments
    __shared__ float sqsh[kL];          // 1KB: B-side sq
    int tid = threadIdx.x;
    int lane = tid & 63, wave = tid >> 6;
    int quad = lane >> 4, l15 = lane & 15;
    int side = blockIdx.y;
    int b = blockIdx.x;                 // b on x: same-b blocks -> same XCD
    const unsigned short* sA = side ? sbf2 : sbf1;
    const unsigned short* sB = side ? sbf1 : sbf2;
    const float* sqA = side ? sq2 : sq1;
    const float* sqB = side ? sq1 : sq2;
    unsigned short* fo = side ? f2 : f1;
    int i0 = blockIdx.z * 128;
    int iw = i0 + wave * 32;
    int lo8 = lane * 8;

    sqsh[tid] = sqB[b * kL + tid];      // covered by the jt=0 staging barrier

    const unsigned short* s1f = sA + ((size_t)(b * 16 + (iw >> 4)) * 4) * 512 + lo8;
    s8_t a1[2][4];
#pragma unroll
    for (int mt = 0; mt < 2; ++mt)
#pragma unroll
        for (int kt = 0; kt < 4; ++kt)
            a1[mt][kt] = *(const s8_t*)(s1f + (size_t)(mt * 4 + kt) * 512);

    float s1c0 = sqA[b * kL + iw + l15];
    float s1c1 = sqA[b * kL + iw + 16 + l15];

    f4_t facc[2][7] = {};

    for (int jt = 0; jt < 2; ++jt) {
        int j0 = jt * 128;
        if (jt) __syncthreads();
        const unsigned short* s2base = sB + ((size_t)(b * 16 + (j0 >> 4)) * 4) * 512;
#pragma unroll
        for (int t = 0; t < 8; ++t) {
            int frag = wave * 8 + t;
            s8_t vld = *(const s8_t*)(s2base + (size_t)frag * 512 + lo8);
            *(s8_t*)(lb + frag * 512 + lo8) = vld;
        }
        __syncthreads();
#pragma unroll
        for (int half = 0; half < 2; ++half) {
            f4_t Dp[4][2] = {};
#pragma unroll
            for (int kt = 0; kt < 4; ++kt) {
                s8_t b2[4];
#pragma unroll
                for (int n = 0; n < 4; ++n)
                    b2[n] = *(const s8_t*)&lb[((half * 4 + n) * 4 + kt) * 512 + lo8];
#pragma unroll
                for (int n = 0; n < 4; ++n)
#pragma unroll
                    for (int mt = 0; mt < 2; ++mt)
                        Dp[n][mt] = __builtin_amdgcn_mfma_f32_16x16x32_bf16(b2[n], a1[mt][kt], Dp[n][mt], 0, 0, 0);
            }
#pragma unroll
            for (int np = 0; np < 2; ++np) {
                int ktj = (j0 >> 5) + half * 2 + np;
                const unsigned short* bp = Wf + (size_t)(ktj * 64 + lane) * 8;
                // af for BOTH mt in one pass: s2q read once (LDS), shared.
                s8_t af0, af1;
#pragma unroll
                for (int h2 = 0; h2 < 2; ++h2) {
                    int n = np * 2 + h2;
#pragma unroll
                    for (int r = 0; r < 4; ++r) {
                        float s2q = sqsh[j0 + half * 64 + n * 16 + quad * 4 + r];
                        float d20 = fmaxf(s2q + s1c0 - 2.f * Dp[n][0][r], 0.f);
                        float d21 = fmaxf(s2q + s1c1 - 2.f * Dp[n][1][r], 0.f);
                        float av0 = __builtin_amdgcn_rcpf(1.f + __builtin_amdgcn_sqrtf(d20));
                        float av1 = __builtin_amdgcn_rcpf(1.f + __builtin_amdgcn_sqrtf(d21));
                        af0[h2 * 4 + r] = (short)f2bf(av0);
                        af1[h2 * 4 + r] = (short)f2bf(av1);
                    }
                }
                // wv loaded ONCE, feeds two independent accumulate chains
#pragma unroll
                for (int nt = 0; nt < 7; ++nt) {
                    s8_t wv = *(const s8_t*)(bp + (size_t)nt * 8 * 64 * 8);
                    facc[0][nt] = __builtin_amdgcn_mfma_f32_16x16x32_bf16(af0, wv, facc[0][nt], 0, 0, 0);
                    facc[1][nt] = __builtin_amdgcn_mfma_f32_16x16x32_bf16(af1, wv, facc[1][nt], 0, 0, 0);
                }
            }
        }
    }
#pragma unroll
    for (int mt = 0; mt < 2; ++mt)
#pragma unroll
        for (int nt = 0; nt < 7; ++nt) {
            int col = nt * 16 + l15;
            if (col < kD) {
#pragma unroll
                for (int r = 0; r < 4; ++r) {
                    size_t row = (size_t)(b * kL) + iw + mt * 16 + quad * 4 + r;
                    fo[row * kD + col] = f2bf(facc[mt][nt][r]);
                }
            }
        }
}

// ------------------------------------------------------------- match row/col sums (pooling weights)
// r25: jt merged in-block (grid (b, itile) = 512 blocks). a1h loaded ONCE
// to regs; w1 row sums complete per block -> plain store (no atomic);
// w2 col sums still atomic between the 2 itile blocks.
__global__ __launch_bounds__(256) void match_sums(const unsigned short* __restrict__ sbf1,
                                                  const unsigned short* __restrict__ sbf2,
                                                  const float* __restrict__ sq1,
                                                  const float* __restrict__ sq2,
                                                  float* __restrict__ w1,
                                                  float* __restrict__ w2) {
    __shared__ short lb[8 * 4 * 512];
    int tid = threadIdx.x;
    int lane = tid & 63, wave = tid >> 6;
    int quad = lane >> 4, l15 = lane & 15;
    int b = blockIdx.x;
    int i0 = blockIdx.y * 128;
    int iw = i0 + wave * 32;
    int lo8 = lane * 8;

    const unsigned short* s1f = sbf1 + ((size_t)(b * 16 + (iw >> 4)) * 4) * 512 + lo8;
    s8_t a1h[2][4];
#pragma unroll
    for (int mt = 0; mt < 2; ++mt)
#pragma unroll
        for (int kt = 0; kt < 4; ++kt)
            a1h[mt][kt] = *(const s8_t*)(s1f + (size_t)(mt * 4 + kt) * 512);

    const float* sq1p = sq1 + b * kL + iw;
    const float* sq2p = sq2 + b * kL;

    float s1v[2][4];
#pragma unroll
    for (int mt = 0; mt < 2; ++mt)
#pragma unroll
        for (int r = 0; r < 4; ++r) s1v[mt][r] = sq1p[mt * 16 + quad * 4 + r];

    float rs_acc[2][4] = {{0.f,0.f,0.f,0.f},{0.f,0.f,0.f,0.f}};

    for (int jt = 0; jt < 2; ++jt) {
        int j0 = jt * 128;
        if (jt) __syncthreads();
        const unsigned short* s2base = sbf2 + ((size_t)(b * 16 + (j0 >> 4)) * 4) * 512;
#pragma unroll
        for (int t = 0; t < 8; ++t) {
            int frag = wave * 8 + t;
            s8_t vld = *(const s8_t*)(s2base + (size_t)frag * 512 + lo8);
            *(s8_t*)(lb + frag * 512 + lo8) = vld;
        }
        __syncthreads();
#pragma unroll
        for (int half = 0; half < 2; ++half) {
            f4_t D[2][4] = {};
#pragma unroll
            for (int kt = 0; kt < 4; ++kt) {
                s8_t b2h[4];
#pragma unroll
                for (int n = 0; n < 4; ++n)
                    b2h[n] = *(const s8_t*)&lb[((half * 4 + n) * 4 + kt) * 512 + lo8];
#pragma unroll
                for (int mt = 0; mt < 2; ++mt)
#pragma unroll
                    for (int n = 0; n < 4; ++n)
                        D[mt][n] = __builtin_amdgcn_mfma_f32_16x16x32_bf16(a1h[mt][kt], b2h[n], D[mt][n], 0, 0, 0);
            }
#pragma unroll
            for (int n = 0; n < 4; ++n) {
                float s2vn = sq2p[j0 + half * 64 + n * 16 + l15];
                float cs = 0.f;
#pragma unroll
                for (int mt = 0; mt < 2; ++mt) {
#pragma unroll
                    for (int r = 0; r < 4; ++r) {
                        float d2 = fmaxf(s1v[mt][r] + s2vn - 2.f * D[mt][n][r], 0.f);
                        float av = __builtin_amdgcn_rcpf(1.f + __builtin_amdgcn_sqrtf(d2));
                        rs_acc[mt][r] += av; cs += av;
                    }
                }
                cs += __shfl_xor(cs, 16, 64);
                cs += __shfl_xor(cs, 32, 64);
                if (lane < 16) atomicAdd(&w2[b * kL + j0 + half * 64 + n * 16 + lane], cs);
            }
        }
    }
#pragma unroll
    for (int mt = 0; mt < 2; ++mt)
#pragma unroll
        for (int r = 0; r < 4; ++r) {
            float v = rs_acc[mt][r];
            v += __shfl_xor(v, 1, 64);
            v += __shfl_xor(v, 2, 64);
            v += __shfl_xor(v, 4, 64);
            v += __shfl_xor(v, 8, 64);
            if (l15 == 0) w1[b * kL + iw + mt * 16 + quad * 4 + r] = v;  // full j coverage: plain store
        }
}

// ------------------------------------------------------------- W -> B-fragment layout (bf16, pi-permuted k)
// r13: one element per thread (the 2-block loop form was latency-serialized).
__global__ __launch_bounds__(256) void wprep_kernel(const float* __restrict__ Ws,
                                                    unsigned short* __restrict__ Wf) {
    int layer = blockIdx.y;
    int t = blockIdx.x * 256 + threadIdx.x;   // grid.x = W_FRAG / 256 = 112
    const float* W = Ws + layer * kL * kD;
    unsigned short* o = Wf + layer * W_FRAG;
    int j = t & 7, lane = (t >> 3) & 63, kt = (t >> 9) & 7, nt = t >> 12;
    int k = kt * 32 + (j >> 2) * 16 + ((lane >> 4) & 3) * 4 + (j & 3);  // pi
    int n = nt * 16 + (lane & 15);
    float v = (n < kD) ? W[k * kD + n] : 0.f;
    o[t] = f2bf(v);
}

// ------------------------------------------------------------- conv(3x3, 2ch) + tanh + mean(1) [+ fused hi prep]
// r24: 32-row tiles. Staging rows 0..33 of halo layout [r][1+d] in 5 passes
// (only pass0 low-check, pass4 high-check); each thread computes 4 output
// rows from 6 staged tap rows per channel (25% fewer LDS reads per row).
__global__ __launch_bounds__(256) void conv_kernel(const float* __restrict__ e1,
                                                   const float* __restrict__ e2,
                                                   const unsigned short* __restrict__ f1,
                                                   const unsigned short* __restrict__ f2,
                                                   const float* __restrict__ ck,
                                                   const float* __restrict__ cb,
                                                   unsigned short* __restrict__ o1,
                                                   unsigned short* __restrict__ o2,
                                                   float* __restrict__ res,
                                                   int ro1, int ro2,
                                                   int do_prep, int do_store,
                                                   const int* __restrict__ q1,
                                                   const int* __restrict__ q2,
                                                   unsigned short* __restrict__ sbf1,
                                                   unsigned short* __restrict__ sbf2,
                                                   float* __restrict__ sq1,
                                                   float* __restrict__ sq2,
                                                   float* __restrict__ w1,
                                                   float* __restrict__ w2) {
    __shared__ float le[34][104];
    __shared__ float lf[34][104];
    __shared__ float pm[8][104];
    __shared__ float vsh[32];
    int tid = threadIdx.x;
    int b = blockIdx.y;
    int l0 = blockIdx.x * 32;
    int side = blockIdx.z;
    const float* e = side ? e2 : e1;
    const unsigned short* f = side ? f2 : f1;
    unsigned short* o = side ? o2 : o1;
    const int* q = side ? q2 : q1;
    unsigned short* sb = side ? sbf2 : sbf1;
    float* sq = side ? sq2 : sq1;
    float* w = side ? w2 : w1;
    int res_off = side ? ro2 : ro1;

    // wave-uniform coefficients -> SGPRs (no LDS, no per-lane reads)
    float ks[18];
#pragma unroll
    for (int i = 0; i < 18; ++i) ks[i] = ck[i];
    float bias = cb[0];

    if (do_prep && tid < 32) {
        vsh[tid] = (q[b * kL + l0 + tid] != 0) ? 1.f : 0.f;
        w[b * kL + l0 + tid] = 0.f;
    }

    // ---- staging: rows 0..33 of halo layout [r][1+d], cols via 26 float4/row.
    // pass0 rows 0..7 (low-bound check), passes 1-3 rows 8..31 (no checks),
    // pass4 rows 32..33 (high-bound check).
    {
        int sc = tid & 31, sr = tid >> 5;
        if (sc < 26) {
            int sc4 = sc * 4;
            long ebase = (long)b * kL * kD + sc4 - 1;   // e has +16-float guard below
            auto stage = [&](int r, int lc, bool ok) {
                long off = ebase + (long)lc * kD;
                float4 v = *(const float4*)(e + off);
                ushort4 u = *(const ushort4*)(f + off);
                float4 g;
                g.x = bf2f(u.x); g.y = bf2f(u.y); g.z = bf2f(u.z); g.w = bf2f(u.w);
                if (!ok) { v.x = 0.f; v.y = 0.f; v.z = 0.f; v.w = 0.f;
                           g.x = 0.f; g.y = 0.f; g.z = 0.f; g.w = 0.f; }
                if (sc == 0)  { v.x = 0.f; g.x = 0.f; }
                if (sc == 25) { v.y = 0.f; v.z = 0.f; v.w = 0.f;
                                g.y = 0.f; g.z = 0.f; g.w = 0.f; }
                *(float4*)&le[r][sc4] = v;
                *(float4*)&lf[r][sc4] = g;
            };
            {
                int l = l0 - 1 + sr;                        // can be -1 only at l0==0
                stage(sr, (l < 0) ? 0 : l, l >= 0);
            }
            stage(sr + 8, l0 + 7 + sr, true);               // rows 8..15, l in [7,238]
            stage(sr + 16, l0 + 15 + sr, true);             // rows 16..23, l in [15,246]
            stage(sr + 24, l0 + 23 + sr, true);             // rows 24..31, l in [23,254]
            if (sr < 2) {
                int l = l0 + 31 + sr;                       // can be 256 only at l0==224
                stage(sr + 32, (l > kL - 1) ? (kL - 1) : l, l <= kL - 1);
            }
        }
    }
    __syncthreads();

    // ---- compute: each act thread = 4 output rows x 4 cols; 6 tap rows x 2ch
    // read once into regs, reused across the 4 output rows.
    int rg = tid >> 5, c4 = tid & 31;
    bool act = c4 < 25;
    int d0 = c4 * 4;
    int r0 = rg * 4;
    float acc[4][4];
    float m4[4] = {0.f, 0.f, 0.f, 0.f};
    if (act) {
#pragma unroll
        for (int rr = 0; rr < 4; ++rr)
#pragma unroll
            for (int jj = 0; jj < 4; ++jj) acc[rr][jj] = bias;
#pragma unroll
        for (int ch = 0; ch < 2; ++ch) {
            const float (*Lr)[104] = ch ? lf : le;
#pragma unroll
            for (int j = 0; j < 6; ++j) {
                float4 v4 = *(const float4*)&Lr[r0 + j][d0];
                float2 v2 = *(const float2*)&Lr[r0 + j][d0 + 4];
#pragma unroll
                for (int rr = 0; rr < 4; ++rr) {
                    int ky = j - rr;
                    if (ky < 0 || ky > 2) continue;
                    float k0 = ks[ch * 9 + ky * 3 + 0];
                    float k1 = ks[ch * 9 + ky * 3 + 1];
                    float k2 = ks[ch * 9 + ky * 3 + 2];
                    acc[rr][0] += k0 * v4.x + k1 * v4.y + k2 * v4.z;
                    acc[rr][1] += k0 * v4.y + k1 * v4.z + k2 * v4.w;
                    acc[rr][2] += k0 * v4.z + k1 * v4.w + k2 * v2.x;
                    acc[rr][3] += k0 * v4.w + k1 * v2.x + k2 * v2.y;
                }
            }
        }
    }

#pragma unroll
    for (int rr = 0; rr < 4; ++rr) {
        int r = r0 + rr;
        float a0 = 0.f, a1 = 0.f, a2 = 0.f, a3 = 0.f;
        if (act) {
            a0 = ftanh(acc[rr][0]); a1 = ftanh(acc[rr][1]);
            a2 = ftanh(acc[rr][2]); a3 = ftanh(acc[rr][3]);
            if (do_store) {
                ushort4 st = {f2bf(a0), f2bf(a1), f2bf(a2), f2bf(a3)};
                *(ushort4*)&o[((size_t)(b * kL) + l0 + r) * kD + d0] = st;
            }
            m4[0] += a0; m4[1] += a1; m4[2] += a2; m4[3] += a3;
        }
        if (do_prep) {
            int row = b * kL + l0 + r;
            float v = vsh[r];
            ushort4 hi = {0, 0, 0, 0};
            float x0 = 0.f, x1 = 0.f, x2 = 0.f, x3 = 0.f;
            if (act) {
                hi.x = f2bf(a0 * v); x0 = bf2f(hi.x);
                hi.y = f2bf(a1 * v); x1 = bf2f(hi.y);
                hi.z = f2bf(a2 * v); x2 = bf2f(hi.z);
                hi.w = f2bf(a3 * v); x3 = bf2f(hi.w);
            }
            float srow = x0 * x0 + x1 * x1 + x2 * x2 + x3 * x3;
#pragma unroll
            for (int m = 16; m >= 1; m >>= 1) srow += __shfl_xor(srow, m, 32);
            if (c4 == 0) sq[row] = srow;
            int kt = c4 >> 3;
            int lfr = ((c4 >> 1) & 3) * 16 + (row & 15);
            unsigned short* p0 = sb + ((size_t)(row >> 4) * 4 + kt) * 512 + lfr * 8 + 4 * (c4 & 1);
            *(ushort4*)p0 = hi;
        }
    }
    if (act) { float4 st = {m4[0], m4[1], m4[2], m4[3]}; *(float4*)&pm[rg][d0] = st; }
    __syncthreads();
    if (tid < kD) {
        float s = 0.f;
#pragma unroll
        for (int g = 0; g < 8; ++g) s += pm[g][tid];
        atomicAdd(&res[b * 600 + res_off + tid], s * (1.0f / kL));
    }
}

// ------------------------------------------------------------- fused: e += avgpool3(o*w); hi prep
// r26: 32-row tiles (halo 34/32; sq/frag stores x2 with row-offset ptrs).
__global__ __launch_bounds__(256) void poolprep_kernel(const unsigned short* __restrict__ o1,
                                                       const unsigned short* __restrict__ o2,
                                                       const float* __restrict__ w1_,
                                                       const float* __restrict__ w2_,
                                                       const int* __restrict__ q1,
                                                       const int* __restrict__ q2,
                                                       float* __restrict__ e1,
                                                       float* __restrict__ e2,
                                                       unsigned short* __restrict__ sbf1,
                                                       unsigned short* __restrict__ sbf2,
                                                       float* __restrict__ sq1,
                                                       float* __restrict__ sq2) {
    __shared__ float tb[34][104];
    __shared__ float xb[32][104];
    __shared__ float vsh[32];
    __shared__ float wsh[34];
    int side = blockIdx.y;
    const unsigned short* o = side ? o2 : o1;
    const float* w = side ? w2_ : w1_;
    const int* q = side ? q2 : q1;
    float* e = side ? e2 : e1;
    unsigned short* sb = side ? sbf2 : sbf1;
    float* sq = side ? sq2 : sq1;
    int tid = threadIdx.x;
    int row0 = blockIdx.x * 32;
    int l0 = row0 & (kL - 1);
    int base_b = row0 - l0;
    if (tid < 34) {
        int l = l0 - 1 + tid;
        wsh[tid] = (l >= 0 && l < kL) ? w[base_b + l] : 0.f;
    }
    if (tid < 32) vsh[tid] = (q[row0 + tid] != 0) ? 1.f : 0.f;
    __syncthreads();
    for (int t = tid; t < 850; t += 256) {     // 34 rows x 25 float4
        int r = t / 25, c = t - r * 25;
        int l = l0 - 1 + r;
        float4 v4 = {0.f, 0.f, 0.f, 0.f};
        if (l >= 0 && l < kL) {
            ushort4 u = *(const ushort4*)(o + (size_t)(base_b + l) * kD + c * 4);
            v4.x = bf2f(u.x); v4.y = bf2f(u.y); v4.z = bf2f(u.z); v4.w = bf2f(u.w);
        }
        float ww = wsh[r];
        tb[r][c * 4 + 0] = v4.x * ww;
        tb[r][c * 4 + 1] = v4.y * ww;
        tb[r][c * 4 + 2] = v4.z * ww;
        tb[r][c * 4 + 3] = v4.w * ww;
    }
    __syncthreads();
    for (int t = tid; t < 800; t += 256) {     // 32 rows x 25 float4
        int r = t / 25, c = t - r * 25;
        float* ep = e + (size_t)(row0 + r) * kD + c * 4;
        float4 e4 = *(float4*)ep;
        float nx = e4.x + (tb[r][c * 4 + 0] + tb[r + 1][c * 4 + 0] + tb[r + 2][c * 4 + 0]) * (1.f / 3.f);
        float ny = e4.y + (tb[r][c * 4 + 1] + tb[r + 1][c * 4 + 1] + tb[r + 2][c * 4 + 1]) * (1.f / 3.f);
        float nz = e4.z + (tb[r][c * 4 + 2] + tb[r + 1][c * 4 + 2] + tb[r + 2][c * 4 + 2]) * (1.f / 3.f);
        float nw = e4.w + (tb[r][c * 4 + 3] + tb[r + 1][c * 4 + 3] + tb[r + 2][c * 4 + 3]) * (1.f / 3.f);
        float4 st = {nx, ny, nz, nw};
        *(float4*)ep = st;
        *(float4*)&xb[r][c * 4] = st;
    }
    __syncthreads();
    sq_store(xb, vsh, sq, row0, tid);
    sq_store(xb + 16, vsh + 16, sq, row0 + 16, tid);
    frag_store(xb, vsh, sb, row0 >> 4, tid);
    frag_store(xb + 16, vsh + 16, sb, (row0 >> 4) + 1, tid);
}

// ------------------------------------------------------------- head
// r25: 512 threads, k split 300/300 across halves; reductions over 8 waves.
__device__ __forceinline__ float block_sum8(float v, float* red, int tid) {
#pragma unroll
    for (int m = 32; m >= 1; m >>= 1) v += __shfl_xor(v, m, 64);
    __syncthreads();
    if ((tid & 63) == 0) red[tid >> 6] = v;
    __syncthreads();
    return red[0] + red[1] + red[2] + red[3] + red[4] + red[5] + red[6] + red[7];
}

__global__ __launch_bounds__(512) void head_kernel(const float* __restrict__ xcat,
                                                   const float* __restrict__ fc1w,
                                                   const float* __restrict__ fc1b,
                                                   const float* __restrict__ lng,
                                                   const float* __restrict__ lnb,
                                                   const float* __restrict__ fc2w,
                                                   const float* __restrict__ fc2b,
                                                   float* __restrict__ out) {
    __shared__ float xr[600];
    __shared__ float hp[512];
    __shared__ float red[8];
    int b = blockIdx.x, tid = threadIdx.x;
    int t8 = tid & 255, kh = tid >> 8;          // kh: which k-half this thread sums
    for (int t = tid; t < 600; t += 512) xr[t] = xcat[b * 600 + t];
    __syncthreads();
    float h0 = kh ? 0.f : fc1b[t8];
    float h1 = kh ? 0.f : fc1b[t8 + 256];
    int kbeg = kh * 300;
    for (int k = kbeg; k < kbeg + 300; ++k) {
        float xv = xr[k];
        h0 = fmaf(xv, fc1w[k * kLIN + t8], h0);
        h1 = fmaf(xv, fc1w[k * kLIN + t8 + 256], h1);
    }
    if (kh) { hp[t8] = h0; hp[t8 + 256] = h1; }
    __syncthreads();
    if (!kh) { h0 += hp[t8]; h1 += hp[t8 + 256]; }
    float mu = block_sum8(kh ? 0.f : (h0 + h1), red, tid) * (1.0f / kLIN);
    float d0 = h0 - mu, d1 = h1 - mu;
    float var = block_sum8(kh ? 0.f : (d0 * d0 + d1 * d1), red, tid) * (1.0f / kLIN);
    float rstd = rsqrtf(var + 1e-5f);
    float n0 = d0 * rstd * lng[t8] + lnb[t8];
    float n1 = d1 * rstd * lng[t8 + 256] + lnb[t8 + 256];
    float r0 = fmaxf(n0, 0.f), r1 = fmaxf(n1, 0.f);
    float p0 = r0 * fc2w[t8 * 2 + 0] + r1 * fc2w[(t8 + 256) * 2 + 0];
    float p1 = r0 * fc2w[t8 * 2 + 1] + r1 * fc2w[(t8 + 256) * 2 + 1];
    float o0 = block_sum8(kh ? 0.f : p0, red, tid);
    float o1 = block_sum8(kh ? 0.f : p1, red, tid);
    if (tid == 0) { out[b * 2 + 0] = o0 + fc2b[0]; out[b * 2 + 1] = o1 + fc2b[1]; }
}

// ----------------------------------------------------------------------------
extern "C" void kernel_launch(void* const* d_in, const int* in_sizes, int n_in,
                              void* d_out, int out_size, void* d_ws, size_t ws_size,
                              hipStream_t stream) {
    const int*   q1   = (const int*)d_in[0];
    const int*   q2   = (const int*)d_in[1];
    const float* emb  = (const float*)d_in[2];
    const float* Ws   = (const float*)d_in[3];
    const float* ck   = (const float*)d_in[4];
    const float* cb   = (const float*)d_in[5];
    const float* fc1w = (const float*)d_in[6];
    const float* fc1b = (const float*)d_in[7];
    const float* lng  = (const float*)d_in[8];
    const float* lnb  = (const float*)d_in[9];
    const float* fc2w = (const float*)d_in[10];
    const float* fc2b = (const float*)d_in[11];
    float* out = (float*)d_out;
    float* ws  = (float*)d_ws;

    float* e1  = ws + 16;                                 // +16 guard: staging reads e-4B
    float* e2  = e1 + SZ_E;
    unsigned short* fb1 = (unsigned short*)(e2 + SZ_E);   // f1|f2 bf16 = SZ_E floats total
    unsigned short* fb2 = fb1 + SZ_E;
    unsigned short* o1  = (unsigned short*)((float*)fb1 + SZ_E);  // o bf16, SZ_E floats total
    unsigned short* o2  = o1 + SZ_E;
    unsigned short* sbf1 = (unsigned short*)((float*)o1 + SZ_E);  // hi-only fragments, 2 sides
    unsigned short* sbf2 = sbf1 + kB * kL * 128;
    float* after = (float*)sbf1 + kB * kL * 128;
    unsigned short* Wfrag = (unsigned short*)after;
    float* sq1 = after + W_FRAG;
    float* sq2 = sq1 + kB * kL;
    float* w1  = sq2 + kB * kL;
    float* w2  = w1 + kB * kL;
    float* xcat = w2 + kB * kL;

    hipMemsetAsync(xcat, 0, kB * 600 * sizeof(float), stream);
    wprep_kernel<<<dim3(W_FRAG / 256, 2), 256, 0, stream>>>(Ws, Wfrag);
    embprep_kernel<<<dim3(kB * kL / 32, 2), 256, 0, stream>>>(q1, q2, emb, e1, e2,
                                                              sbf1, sbf2, sq1, sq2, xcat);

    // ---- layer 0  (matchf/match_sums grids: b on x -> same-b blocks share an XCD)
    matchf_kernel<<<dim3(kB, 2, 2), 256, 0, stream>>>(sbf1, sbf2, sq1, sq2, Wfrag, fb1, fb2);
    conv_kernel<<<dim3(kL / 32, kB, 2), 256, 0, stream>>>(e1, e2, fb1, fb2, ck, cb,
                                                          o1, o2, xcat, 100, 400,
                                                          1, 1, q1, q2, sbf1, sbf2, sq1, sq2, w1, w2);
    match_sums<<<dim3(kB, 2), 256, 0, stream>>>(sbf1, sbf2, sq1, sq2, w1, w2);
    poolprep_kernel<<<dim3(kB * kL / 32, 2), 256, 0, stream>>>(o1, o2, w1, w2, q1, q2,
                                                               e1, e2, sbf1, sbf2, sq1, sq2);
    // ---- layer 1 (tail match/pool dead; o-store also dead)
    matchf_kernel<<<dim3(kB, 2, 2), 256, 0, stream>>>(sbf1, sbf2, sq1, sq2, Wfrag + W_FRAG, fb1, fb2);
    conv_kernel<<<dim3(kL / 32, kB, 2), 256, 0, stream>>>(e1, e2, fb1, fb2, ck + 18, cb + 1,
                                                          o1, o2, xcat, 200, 500,
                                                          0, 0, q1, q2, sbf1, sbf2, sq1, sq2, w1, w2);

    head_kernel<<<kB, 512, 0, stream>>>(xcat, fc1w, fc1b, lng, lnb, fc2w, fc2b, out);
}

// Round 14
// 304.431 us; speedup vs baseline: 1.0289x; 1.0289x over previous
//
#include <hip/hip_runtime.h>
#include <hip/hip_bf16.h>
#include <math.h>

// Problem constants
static constexpr int kB = 256;
static constexpr int kL = 256;
static constexpr int kD = 100;
static constexpr int kLIN = 512;
static constexpr int SZ_E = kB * kL * kD;     // 6,553,600
static constexpr int W_FRAG = 7 * 8 * 64 * 8; // 28672 bf16 per layer

typedef short  s8_t  __attribute__((ext_vector_type(8)));
typedef float  f4_t  __attribute__((ext_vector_type(4)));

// sbf fragment storage (hi-only bf16): rowgroup g = row>>4, slot s in [0,4):
//   ((size_t)g*4 + s)*512 shorts, lane = quad*16 + (row&15), 8 shorts/lane,
//   k = s*32 + quad*8 + j (identity). sq from the SAME bf16-rounded values.
// W fragments pi-permuted (wprep); matchf's Dp registers feed the f-GEMM MFMA.
// matchf CLOSED at r19 (41.3us): stage+XCD-grid; monolith/no-LDS/gload_lds/
// batching+setprio all worse (r16-r23). NEVER use __launch_bounds__(256,4)
// on >=100-VGPR kernels (caps VGPR at 64 -> scratch spills, r20).
// conv r24: 32-row tiles (reuse-heavy -> tile growth pays).
// r25: match_sums jt-merge (w1 plain store) + head k-split (-> 306.2us BEST).
// r26 FALSIFIED (313.2): 32-row embprep/poolprep regressed -- those kernels
// are streaming (no per-element LDS reuse), so bigger tiles only cost TLP
// (poolprep 27.7KB LDS -> 5 blocks/CU) + serial tails. Tile growth pays
// ONLY where reuse scales with tile size. r27 = exact revert to the r25
// build (session best).

__device__ __forceinline__ unsigned short f2bf(float x) {
    __hip_bfloat16 h = __float2bfloat16(x);
    return *(unsigned short*)&h;
}
__device__ __forceinline__ float bf2f(unsigned short u) {
    unsigned int w = ((unsigned int)u) << 16;
    return *(float*)&w;
}
__device__ __forceinline__ float ftanh(float x) {
    // tanh(|x|) = (1 - e^{-2|x|}) / (1 + e^{-2|x|}); rcp instead of IEEE div.
    float ax = fabsf(x);
    float t = __expf(-2.f * ax);
    float r = (1.f - t) * __builtin_amdgcn_rcpf(1.f + t);
    return copysignf(r, x);
}

// write one rowgroup (16 rows in rb[16][104]) as 4 coalesced hi fragments (one per wave)
__device__ __forceinline__ void frag_store(const float (*rb)[104], const float* vsh,
                                           unsigned short* sb, int g, int tid) {
    int lane = tid & 63, wave = tid >> 6;   // wave = slot
    int qd = (lane >> 4) & 3, r15 = lane & 15;
    float v = vsh[r15];
    int kbase = wave * 32 + qd * 8;
    s8_t stv;
#pragma unroll
    for (int j = 0; j < 8; ++j) {
        int k = kbase + j;
        float x = (k < kD) ? rb[r15][k] * v : 0.f;
        stv[j] = (short)f2bf(x);
    }
    *(s8_t*)(sb + ((size_t)g * 4 + wave) * 512 + lane * 8) = stv;
}

// per-row sum of squares of bf16-ROUNDED masked values (16 threads/row)
__device__ __forceinline__ void sq_store(const float (*rb)[104], const float* vsh,
                                         float* sq, int row0, int tid) {
    int r = tid >> 4, j = tid & 15;
    float v = vsh[r];
    float s = 0.f;
    for (int d = j; d < kD; d += 16) { float x = bf2f(f2bf(rb[r][d] * v)); s += x * x; }
#pragma unroll
    for (int m = 8; m >= 1; m >>= 1) s += __shfl_xor(s, m, 64);
    if (j == 0) sq[row0 + r] = s;
}

// ------------------------------------------------------------- embed + prep + fused mean
__global__ __launch_bounds__(256) void embprep_kernel(const int* __restrict__ q1,
                                                      const int* __restrict__ q2,
                                                      const float* __restrict__ emb,
                                                      float* __restrict__ e1,
                                                      float* __restrict__ e2,
                                                      unsigned short* __restrict__ sbf1,
                                                      unsigned short* __restrict__ sbf2,
                                                      float* __restrict__ sq1,
                                                      float* __restrict__ sq2,
                                                      float* __restrict__ xcat) {
    __shared__ float rb[16][104];
    __shared__ float vsh[16];
    int side = blockIdx.y;
    const int* q = side ? q2 : q1;
    float* e = side ? e2 : e1;
    unsigned short* sb = side ? sbf2 : sbf1;
    float* sq = side ? sq2 : sq1;
    int tid = threadIdx.x;
    int row0 = blockIdx.x * 16;
    int b = row0 >> 8;
    if (tid < 16) vsh[tid] = (q[row0 + tid] != 0) ? 1.f : 0.f;
    for (int t = tid; t < 400; t += 256) {
        int r = t / 25, c = t - r * 25;
        int qv = q[row0 + r];
        float4 v4 = *(const float4*)(emb + (size_t)qv * kD + c * 4);
        *(float4*)(e + (size_t)(row0 + r) * kD + c * 4) = v4;
        *(float4*)&rb[r][c * 4] = v4;
    }
    __syncthreads();
    sq_store(rb, vsh, sq, row0, tid);
    if (tid < kD) {
        float s = 0.f;
#pragma unroll
        for (int r = 0; r < 16; ++r) s += rb[r][tid];
        atomicAdd(&xcat[b * 600 + side * 300 + tid], s * (1.0f / kL));
    }
    frag_store(rb, vsh, sb, row0 >> 4, tid);
}

// ------------------------------------------------------------- fused match + f-GEMM
// r19 FINAL: r15 body; grid (b, side, itile) so all 4 blocks of a b share one XCD L2.
__global__ __launch_bounds__(256) void matchf_kernel(const unsigned short* __restrict__ sbf1,
                                                     const unsigned short* __restrict__ sbf2,
                                                     const float* __restrict__ sq1,
                                                     const float* __restrict__ sq2,
                                                     const unsigned short* __restrict__ Wf,
                                                     unsigned short* __restrict__ f1,
                                                     unsigned short* __restrict__ f2) {
    __shared__ short lb[8 * 4 * 512];   // 32KB: contraction-side fragments
    __shared__ float sqsh[kL];          // 1KB: B-side sq
    int tid = threadIdx.x;
    int lane = tid & 63, wave = tid >> 6;
    int quad = lane >> 4, l15 = lane & 15;
    int side = blockIdx.y;
    int b = blockIdx.x;                 // b on x: same-b blocks -> same XCD
    const unsigned short* sA = side ? sbf2 : sbf1;
    const unsigned short* sB = side ? sbf1 : sbf2;
    const float* sqA = side ? sq2 : sq1;
    const float* sqB = side ? sq1 : sq2;
    unsigned short* fo = side ? f2 : f1;
    int i0 = blockIdx.z * 128;
    int iw = i0 + wave * 32;
    int lo8 = lane * 8;

    sqsh[tid] = sqB[b * kL + tid];      // covered by the jt=0 staging barrier

    const unsigned short* s1f = sA + ((size_t)(b * 16 + (iw >> 4)) * 4) * 512 + lo8;
    s8_t a1[2][4];
#pragma unroll
    for (int mt = 0; mt < 2; ++mt)
#pragma unroll
        for (int kt = 0; kt < 4; ++kt)
            a1[mt][kt] = *(const s8_t*)(s1f + (size_t)(mt * 4 + kt) * 512);

    float s1c0 = sqA[b * kL + iw + l15];
    float s1c1 = sqA[b * kL + iw + 16 + l15];

    f4_t facc[2][7] = {};

    for (int jt = 0; jt < 2; ++jt) {
        int j0 = jt * 128;
        if (jt) __syncthreads();
        const unsigned short* s2base = sB + ((size_t)(b * 16 + (j0 >> 4)) * 4) * 512;
#pragma unroll
        for (int t = 0; t < 8; ++t) {
            int frag = wave * 8 + t;
            s8_t vld = *(const s8_t*)(s2base + (size_t)frag * 512 + lo8);
            *(s8_t*)(lb + frag * 512 + lo8) = vld;
        }
        __syncthreads();
#pragma unroll
        for (int half = 0; half < 2; ++half) {
            f4_t Dp[4][2] = {};
#pragma unroll
            for (int kt = 0; kt < 4; ++kt) {
                s8_t b2[4];
#pragma unroll
                for (int n = 0; n < 4; ++n)
                    b2[n] = *(const s8_t*)&lb[((half * 4 + n) * 4 + kt) * 512 + lo8];
#pragma unroll
                for (int n = 0; n < 4; ++n)
#pragma unroll
                    for (int mt = 0; mt < 2; ++mt)
                        Dp[n][mt] = __builtin_amdgcn_mfma_f32_16x16x32_bf16(b2[n], a1[mt][kt], Dp[n][mt], 0, 0, 0);
            }
#pragma unroll
            for (int np = 0; np < 2; ++np) {
                int ktj = (j0 >> 5) + half * 2 + np;
                const unsigned short* bp = Wf + (size_t)(ktj * 64 + lane) * 8;
                // af for BOTH mt in one pass: s2q read once (LDS), shared.
                s8_t af0, af1;
#pragma unroll
                for (int h2 = 0; h2 < 2; ++h2) {
                    int n = np * 2 + h2;
#pragma unroll
                    for (int r = 0; r < 4; ++r) {
                        float s2q = sqsh[j0 + half * 64 + n * 16 + quad * 4 + r];
                        float d20 = fmaxf(s2q + s1c0 - 2.f * Dp[n][0][r], 0.f);
                        float d21 = fmaxf(s2q + s1c1 - 2.f * Dp[n][1][r], 0.f);
                        float av0 = __builtin_amdgcn_rcpf(1.f + __builtin_amdgcn_sqrtf(d20));
                        float av1 = __builtin_amdgcn_rcpf(1.f + __builtin_amdgcn_sqrtf(d21));
                        af0[h2 * 4 + r] = (short)f2bf(av0);
                        af1[h2 * 4 + r] = (short)f2bf(av1);
                    }
                }
                // wv loaded ONCE, feeds two independent accumulate chains
#pragma unroll
                for (int nt = 0; nt < 7; ++nt) {
                    s8_t wv = *(const s8_t*)(bp + (size_t)nt * 8 * 64 * 8);
                    facc[0][nt] = __builtin_amdgcn_mfma_f32_16x16x32_bf16(af0, wv, facc[0][nt], 0, 0, 0);
                    facc[1][nt] = __builtin_amdgcn_mfma_f32_16x16x32_bf16(af1, wv, facc[1][nt], 0, 0, 0);
                }
            }
        }
    }
#pragma unroll
    for (int mt = 0; mt < 2; ++mt)
#pragma unroll
        for (int nt = 0; nt < 7; ++nt) {
            int col = nt * 16 + l15;
            if (col < kD) {
#pragma unroll
                for (int r = 0; r < 4; ++r) {
                    size_t row = (size_t)(b * kL) + iw + mt * 16 + quad * 4 + r;
                    fo[row * kD + col] = f2bf(facc[mt][nt][r]);
                }
            }
        }
}

// ------------------------------------------------------------- match row/col sums (pooling weights)
// r25: jt merged in-block (grid (b, itile) = 512 blocks). a1h loaded ONCE
// to regs; w1 row sums complete per block -> plain store (no atomic);
// w2 col sums still atomic between the 2 itile blocks.
__global__ __launch_bounds__(256) void match_sums(const unsigned short* __restrict__ sbf1,
                                                  const unsigned short* __restrict__ sbf2,
                                                  const float* __restrict__ sq1,
                                                  const float* __restrict__ sq2,
                                                  float* __restrict__ w1,
                                                  float* __restrict__ w2) {
    __shared__ short lb[8 * 4 * 512];
    int tid = threadIdx.x;
    int lane = tid & 63, wave = tid >> 6;
    int quad = lane >> 4, l15 = lane & 15;
    int b = blockIdx.x;
    int i0 = blockIdx.y * 128;
    int iw = i0 + wave * 32;
    int lo8 = lane * 8;

    const unsigned short* s1f = sbf1 + ((size_t)(b * 16 + (iw >> 4)) * 4) * 512 + lo8;
    s8_t a1h[2][4];
#pragma unroll
    for (int mt = 0; mt < 2; ++mt)
#pragma unroll
        for (int kt = 0; kt < 4; ++kt)
            a1h[mt][kt] = *(const s8_t*)(s1f + (size_t)(mt * 4 + kt) * 512);

    const float* sq1p = sq1 + b * kL + iw;
    const float* sq2p = sq2 + b * kL;

    float s1v[2][4];
#pragma unroll
    for (int mt = 0; mt < 2; ++mt)
#pragma unroll
        for (int r = 0; r < 4; ++r) s1v[mt][r] = sq1p[mt * 16 + quad * 4 + r];

    float rs_acc[2][4] = {{0.f,0.f,0.f,0.f},{0.f,0.f,0.f,0.f}};

    for (int jt = 0; jt < 2; ++jt) {
        int j0 = jt * 128;
        if (jt) __syncthreads();
        const unsigned short* s2base = sbf2 + ((size_t)(b * 16 + (j0 >> 4)) * 4) * 512;
#pragma unroll
        for (int t = 0; t < 8; ++t) {
            int frag = wave * 8 + t;
            s8_t vld = *(const s8_t*)(s2base + (size_t)frag * 512 + lo8);
            *(s8_t*)(lb + frag * 512 + lo8) = vld;
        }
        __syncthreads();
#pragma unroll
        for (int half = 0; half < 2; ++half) {
            f4_t D[2][4] = {};
#pragma unroll
            for (int kt = 0; kt < 4; ++kt) {
                s8_t b2h[4];
#pragma unroll
                for (int n = 0; n < 4; ++n)
                    b2h[n] = *(const s8_t*)&lb[((half * 4 + n) * 4 + kt) * 512 + lo8];
#pragma unroll
                for (int mt = 0; mt < 2; ++mt)
#pragma unroll
                    for (int n = 0; n < 4; ++n)
                        D[mt][n] = __builtin_amdgcn_mfma_f32_16x16x32_bf16(a1h[mt][kt], b2h[n], D[mt][n], 0, 0, 0);
            }
#pragma unroll
            for (int n = 0; n < 4; ++n) {
                float s2vn = sq2p[j0 + half * 64 + n * 16 + l15];
                float cs = 0.f;
#pragma unroll
                for (int mt = 0; mt < 2; ++mt) {
#pragma unroll
                    for (int r = 0; r < 4; ++r) {
                        float d2 = fmaxf(s1v[mt][r] + s2vn - 2.f * D[mt][n][r], 0.f);
                        float av = __builtin_amdgcn_rcpf(1.f + __builtin_amdgcn_sqrtf(d2));
                        rs_acc[mt][r] += av; cs += av;
                    }
                }
                cs += __shfl_xor(cs, 16, 64);
                cs += __shfl_xor(cs, 32, 64);
                if (lane < 16) atomicAdd(&w2[b * kL + j0 + half * 64 + n * 16 + lane], cs);
            }
        }
    }
#pragma unroll
    for (int mt = 0; mt < 2; ++mt)
#pragma unroll
        for (int r = 0; r < 4; ++r) {
            float v = rs_acc[mt][r];
            v += __shfl_xor(v, 1, 64);
            v += __shfl_xor(v, 2, 64);
            v += __shfl_xor(v, 4, 64);
            v += __shfl_xor(v, 8, 64);
            if (l15 == 0) w1[b * kL + iw + mt * 16 + quad * 4 + r] = v;  // full j coverage: plain store
        }
}

// ------------------------------------------------------------- W -> B-fragment layout (bf16, pi-permuted k)
// r13: one element per thread (the 2-block loop form was latency-serialized).
__global__ __launch_bounds__(256) void wprep_kernel(const float* __restrict__ Ws,
                                                    unsigned short* __restrict__ Wf) {
    int layer = blockIdx.y;
    int t = blockIdx.x * 256 + threadIdx.x;   // grid.x = W_FRAG / 256 = 112
    const float* W = Ws + layer * kL * kD;
    unsigned short* o = Wf + layer * W_FRAG;
    int j = t & 7, lane = (t >> 3) & 63, kt = (t >> 9) & 7, nt = t >> 12;
    int k = kt * 32 + (j >> 2) * 16 + ((lane >> 4) & 3) * 4 + (j & 3);  // pi
    int n = nt * 16 + (lane & 15);
    float v = (n < kD) ? W[k * kD + n] : 0.f;
    o[t] = f2bf(v);
}

// ------------------------------------------------------------- conv(3x3, 2ch) + tanh + mean(1) [+ fused hi prep]
// r24: 32-row tiles. Staging rows 0..33 of halo layout [r][1+d] in 5 passes
// (only pass0 low-check, pass4 high-check); each thread computes 4 output
// rows from 6 staged tap rows per channel (25% fewer LDS reads per row).
__global__ __launch_bounds__(256) void conv_kernel(const float* __restrict__ e1,
                                                   const float* __restrict__ e2,
                                                   const unsigned short* __restrict__ f1,
                                                   const unsigned short* __restrict__ f2,
                                                   const float* __restrict__ ck,
                                                   const float* __restrict__ cb,
                                                   unsigned short* __restrict__ o1,
                                                   unsigned short* __restrict__ o2,
                                                   float* __restrict__ res,
                                                   int ro1, int ro2,
                                                   int do_prep, int do_store,
                                                   const int* __restrict__ q1,
                                                   const int* __restrict__ q2,
                                                   unsigned short* __restrict__ sbf1,
                                                   unsigned short* __restrict__ sbf2,
                                                   float* __restrict__ sq1,
                                                   float* __restrict__ sq2,
                                                   float* __restrict__ w1,
                                                   float* __restrict__ w2) {
    __shared__ float le[34][104];
    __shared__ float lf[34][104];
    __shared__ float pm[8][104];
    __shared__ float vsh[32];
    int tid = threadIdx.x;
    int b = blockIdx.y;
    int l0 = blockIdx.x * 32;
    int side = blockIdx.z;
    const float* e = side ? e2 : e1;
    const unsigned short* f = side ? f2 : f1;
    unsigned short* o = side ? o2 : o1;
    const int* q = side ? q2 : q1;
    unsigned short* sb = side ? sbf2 : sbf1;
    float* sq = side ? sq2 : sq1;
    float* w = side ? w2 : w1;
    int res_off = side ? ro2 : ro1;

    // wave-uniform coefficients -> SGPRs (no LDS, no per-lane reads)
    float ks[18];
#pragma unroll
    for (int i = 0; i < 18; ++i) ks[i] = ck[i];
    float bias = cb[0];

    if (do_prep && tid < 32) {
        vsh[tid] = (q[b * kL + l0 + tid] != 0) ? 1.f : 0.f;
        w[b * kL + l0 + tid] = 0.f;
    }

    // ---- staging: rows 0..33 of halo layout [r][1+d], cols via 26 float4/row.
    // pass0 rows 0..7 (low-bound check), passes 1-3 rows 8..31 (no checks),
    // pass4 rows 32..33 (high-bound check).
    {
        int sc = tid & 31, sr = tid >> 5;
        if (sc < 26) {
            int sc4 = sc * 4;
            long ebase = (long)b * kL * kD + sc4 - 1;   // e has +16-float guard below
            auto stage = [&](int r, int lc, bool ok) {
                long off = ebase + (long)lc * kD;
                float4 v = *(const float4*)(e + off);
                ushort4 u = *(const ushort4*)(f + off);
                float4 g;
                g.x = bf2f(u.x); g.y = bf2f(u.y); g.z = bf2f(u.z); g.w = bf2f(u.w);
                if (!ok) { v.x = 0.f; v.y = 0.f; v.z = 0.f; v.w = 0.f;
                           g.x = 0.f; g.y = 0.f; g.z = 0.f; g.w = 0.f; }
                if (sc == 0)  { v.x = 0.f; g.x = 0.f; }
                if (sc == 25) { v.y = 0.f; v.z = 0.f; v.w = 0.f;
                                g.y = 0.f; g.z = 0.f; g.w = 0.f; }
                *(float4*)&le[r][sc4] = v;
                *(float4*)&lf[r][sc4] = g;
            };
            {
                int l = l0 - 1 + sr;                        // can be -1 only at l0==0
                stage(sr, (l < 0) ? 0 : l, l >= 0);
            }
            stage(sr + 8, l0 + 7 + sr, true);               // rows 8..15, l in [7,238]
            stage(sr + 16, l0 + 15 + sr, true);             // rows 16..23, l in [15,246]
            stage(sr + 24, l0 + 23 + sr, true);             // rows 24..31, l in [23,254]
            if (sr < 2) {
                int l = l0 + 31 + sr;                       // can be 256 only at l0==224
                stage(sr + 32, (l > kL - 1) ? (kL - 1) : l, l <= kL - 1);
            }
        }
    }
    __syncthreads();

    // ---- compute: each act thread = 4 output rows x 4 cols; 6 tap rows x 2ch
    // read once into regs, reused across the 4 output rows.
    int rg = tid >> 5, c4 = tid & 31;
    bool act = c4 < 25;
    int d0 = c4 * 4;
    int r0 = rg * 4;
    float acc[4][4];
    float m4[4] = {0.f, 0.f, 0.f, 0.f};
    if (act) {
#pragma unroll
        for (int rr = 0; rr < 4; ++rr)
#pragma unroll
            for (int jj = 0; jj < 4; ++jj) acc[rr][jj] = bias;
#pragma unroll
        for (int ch = 0; ch < 2; ++ch) {
            const float (*Lr)[104] = ch ? lf : le;
#pragma unroll
            for (int j = 0; j < 6; ++j) {
                float4 v4 = *(const float4*)&Lr[r0 + j][d0];
                float2 v2 = *(const float2*)&Lr[r0 + j][d0 + 4];
#pragma unroll
                for (int rr = 0; rr < 4; ++rr) {
                    int ky = j - rr;
                    if (ky < 0 || ky > 2) continue;
                    float k0 = ks[ch * 9 + ky * 3 + 0];
                    float k1 = ks[ch * 9 + ky * 3 + 1];
                    float k2 = ks[ch * 9 + ky * 3 + 2];
                    acc[rr][0] += k0 * v4.x + k1 * v4.y + k2 * v4.z;
                    acc[rr][1] += k0 * v4.y + k1 * v4.z + k2 * v4.w;
                    acc[rr][2] += k0 * v4.z + k1 * v4.w + k2 * v2.x;
                    acc[rr][3] += k0 * v4.w + k1 * v2.x + k2 * v2.y;
                }
            }
        }
    }

#pragma unroll
    for (int rr = 0; rr < 4; ++rr) {
        int r = r0 + rr;
        float a0 = 0.f, a1 = 0.f, a2 = 0.f, a3 = 0.f;
        if (act) {
            a0 = ftanh(acc[rr][0]); a1 = ftanh(acc[rr][1]);
            a2 = ftanh(acc[rr][2]); a3 = ftanh(acc[rr][3]);
            if (do_store) {
                ushort4 st = {f2bf(a0), f2bf(a1), f2bf(a2), f2bf(a3)};
                *(ushort4*)&o[((size_t)(b * kL) + l0 + r) * kD + d0] = st;
            }
            m4[0] += a0; m4[1] += a1; m4[2] += a2; m4[3] += a3;
        }
        if (do_prep) {
            int row = b * kL + l0 + r;
            float v = vsh[r];
            ushort4 hi = {0, 0, 0, 0};
            float x0 = 0.f, x1 = 0.f, x2 = 0.f, x3 = 0.f;
            if (act) {
                hi.x = f2bf(a0 * v); x0 = bf2f(hi.x);
                hi.y = f2bf(a1 * v); x1 = bf2f(hi.y);
                hi.z = f2bf(a2 * v); x2 = bf2f(hi.z);
                hi.w = f2bf(a3 * v); x3 = bf2f(hi.w);
            }
            float srow = x0 * x0 + x1 * x1 + x2 * x2 + x3 * x3;
#pragma unroll
            for (int m = 16; m >= 1; m >>= 1) srow += __shfl_xor(srow, m, 32);
            if (c4 == 0) sq[row] = srow;
            int kt = c4 >> 3;
            int lfr = ((c4 >> 1) & 3) * 16 + (row & 15);
            unsigned short* p0 = sb + ((size_t)(row >> 4) * 4 + kt) * 512 + lfr * 8 + 4 * (c4 & 1);
            *(ushort4*)p0 = hi;
        }
    }
    if (act) { float4 st = {m4[0], m4[1], m4[2], m4[3]}; *(float4*)&pm[rg][d0] = st; }
    __syncthreads();
    if (tid < kD) {
        float s = 0.f;
#pragma unroll
        for (int g = 0; g < 8; ++g) s += pm[g][tid];
        atomicAdd(&res[b * 600 + res_off + tid], s * (1.0f / kL));
    }
}

// ------------------------------------------------------------- fused: e += avgpool3(o*w); hi prep (16-row blocks)
__global__ __launch_bounds__(256) void poolprep_kernel(const unsigned short* __restrict__ o1,
                                                       const unsigned short* __restrict__ o2,
                                                       const float* __restrict__ w1_,
                                                       const float* __restrict__ w2_,
                                                       const int* __restrict__ q1,
                                                       const int* __restrict__ q2,
                                                       float* __restrict__ e1,
                                                       float* __restrict__ e2,
                                                       unsigned short* __restrict__ sbf1,
                                                       unsigned short* __restrict__ sbf2,
                                                       float* __restrict__ sq1,
                                                       float* __restrict__ sq2) {
    __shared__ float tb[18][104];
    __shared__ float xb[16][104];
    __shared__ float vsh[16];
    __shared__ float wsh[18];
    int side = blockIdx.y;
    const unsigned short* o = side ? o2 : o1;
    const float* w = side ? w2_ : w1_;
    const int* q = side ? q2 : q1;
    float* e = side ? e2 : e1;
    unsigned short* sb = side ? sbf2 : sbf1;
    float* sq = side ? sq2 : sq1;
    int tid = threadIdx.x;
    int row0 = blockIdx.x * 16;
    int l0 = row0 & (kL - 1);
    int base_b = row0 - l0;
    if (tid < 18) {
        int l = l0 - 1 + tid;
        wsh[tid] = (l >= 0 && l < kL) ? w[base_b + l] : 0.f;
    }
    if (tid < 16) vsh[tid] = (q[row0 + tid] != 0) ? 1.f : 0.f;
    __syncthreads();
    for (int t = tid; t < 450; t += 256) {
        int r = t / 25, c = t - r * 25;
        int l = l0 - 1 + r;
        float4 v4 = {0.f, 0.f, 0.f, 0.f};
        if (l >= 0 && l < kL) {
            ushort4 u = *(const ushort4*)(o + (size_t)(base_b + l) * kD + c * 4);
            v4.x = bf2f(u.x); v4.y = bf2f(u.y); v4.z = bf2f(u.z); v4.w = bf2f(u.w);
        }
        float ww = wsh[r];
        tb[r][c * 4 + 0] = v4.x * ww;
        tb[r][c * 4 + 1] = v4.y * ww;
        tb[r][c * 4 + 2] = v4.z * ww;
        tb[r][c * 4 + 3] = v4.w * ww;
    }
    __syncthreads();
    for (int t = tid; t < 400; t += 256) {
        int r = t / 25, c = t - r * 25;
        float* ep = e + (size_t)(row0 + r) * kD + c * 4;
        float4 e4 = *(float4*)ep;
        float nx = e4.x + (tb[r][c * 4 + 0] + tb[r + 1][c * 4 + 0] + tb[r + 2][c * 4 + 0]) * (1.f / 3.f);
        float ny = e4.y + (tb[r][c * 4 + 1] + tb[r + 1][c * 4 + 1] + tb[r + 2][c * 4 + 1]) * (1.f / 3.f);
        float nz = e4.z + (tb[r][c * 4 + 2] + tb[r + 1][c * 4 + 2] + tb[r + 2][c * 4 + 2]) * (1.f / 3.f);
        float nw = e4.w + (tb[r][c * 4 + 3] + tb[r + 1][c * 4 + 3] + tb[r + 2][c * 4 + 3]) * (1.f / 3.f);
        float4 st = {nx, ny, nz, nw};
        *(float4*)ep = st;
        *(float4*)&xb[r][c * 4] = st;
    }
    __syncthreads();
    sq_store(xb, vsh, sq, row0, tid);
    frag_store(xb, vsh, sb, row0 >> 4, tid);
}

// ------------------------------------------------------------- head
// r25: 512 threads, k split 300/300 across halves; reductions over 8 waves.
__device__ __forceinline__ float block_sum8(float v, float* red, int tid) {
#pragma unroll
    for (int m = 32; m >= 1; m >>= 1) v += __shfl_xor(v, m, 64);
    __syncthreads();
    if ((tid & 63) == 0) red[tid >> 6] = v;
    __syncthreads();
    return red[0] + red[1] + red[2] + red[3] + red[4] + red[5] + red[6] + red[7];
}

__global__ __launch_bounds__(512) void head_kernel(const float* __restrict__ xcat,
                                                   const float* __restrict__ fc1w,
                                                   const float* __restrict__ fc1b,
                                                   const float* __restrict__ lng,
                                                   const float* __restrict__ lnb,
                                                   const float* __restrict__ fc2w,
                                                   const float* __restrict__ fc2b,
                                                   float* __restrict__ out) {
    __shared__ float xr[600];
    __shared__ float hp[512];
    __shared__ float red[8];
    int b = blockIdx.x, tid = threadIdx.x;
    int t8 = tid & 255, kh = tid >> 8;          // kh: which k-half this thread sums
    for (int t = tid; t < 600; t += 512) xr[t] = xcat[b * 600 + t];
    __syncthreads();
    float h0 = kh ? 0.f : fc1b[t8];
    float h1 = kh ? 0.f : fc1b[t8 + 256];
    int kbeg = kh * 300;
    for (int k = kbeg; k < kbeg + 300; ++k) {
        float xv = xr[k];
        h0 = fmaf(xv, fc1w[k * kLIN + t8], h0);
        h1 = fmaf(xv, fc1w[k * kLIN + t8 + 256], h1);
    }
    if (kh) { hp[t8] = h0; hp[t8 + 256] = h1; }
    __syncthreads();
    if (!kh) { h0 += hp[t8]; h1 += hp[t8 + 256]; }
    float mu = block_sum8(kh ? 0.f : (h0 + h1), red, tid) * (1.0f / kLIN);
    float d0 = h0 - mu, d1 = h1 - mu;
    float var = block_sum8(kh ? 0.f : (d0 * d0 + d1 * d1), red, tid) * (1.0f / kLIN);
    float rstd = rsqrtf(var + 1e-5f);
    float n0 = d0 * rstd * lng[t8] + lnb[t8];
    float n1 = d1 * rstd * lng[t8 + 256] + lnb[t8 + 256];
    float r0 = fmaxf(n0, 0.f), r1 = fmaxf(n1, 0.f);
    float p0 = r0 * fc2w[t8 * 2 + 0] + r1 * fc2w[(t8 + 256) * 2 + 0];
    float p1 = r0 * fc2w[t8 * 2 + 1] + r1 * fc2w[(t8 + 256) * 2 + 1];
    float o0 = block_sum8(kh ? 0.f : p0, red, tid);
    float o1 = block_sum8(kh ? 0.f : p1, red, tid);
    if (tid == 0) { out[b * 2 + 0] = o0 + fc2b[0]; out[b * 2 + 1] = o1 + fc2b[1]; }
}

// ----------------------------------------------------------------------------
extern "C" void kernel_launch(void* const* d_in, const int* in_sizes, int n_in,
                              void* d_out, int out_size, void* d_ws, size_t ws_size,
                              hipStream_t stream) {
    const int*   q1   = (const int*)d_in[0];
    const int*   q2   = (const int*)d_in[1];
    const float* emb  = (const float*)d_in[2];
    const float* Ws   = (const float*)d_in[3];
    const float* ck   = (const float*)d_in[4];
    const float* cb   = (const float*)d_in[5];
    const float* fc1w = (const float*)d_in[6];
    const float* fc1b = (const float*)d_in[7];
    const float* lng  = (const float*)d_in[8];
    const float* lnb  = (const float*)d_in[9];
    const float* fc2w = (const float*)d_in[10];
    const float* fc2b = (const float*)d_in[11];
    float* out = (float*)d_out;
    float* ws  = (float*)d_ws;

    float* e1  = ws + 16;                                 // +16 guard: staging reads e-4B
    float* e2  = e1 + SZ_E;
    unsigned short* fb1 = (unsigned short*)(e2 + SZ_E);   // f1|f2 bf16 = SZ_E floats total
    unsigned short* fb2 = fb1 + SZ_E;
    unsigned short* o1  = (unsigned short*)((float*)fb1 + SZ_E);  // o bf16, SZ_E floats total
    unsigned short* o2  = o1 + SZ_E;
    unsigned short* sbf1 = (unsigned short*)((float*)o1 + SZ_E);  // hi-only fragments, 2 sides
    unsigned short* sbf2 = sbf1 + kB * kL * 128;
    float* after = (float*)sbf1 + kB * kL * 128;
    unsigned short* Wfrag = (unsigned short*)after;
    float* sq1 = after + W_FRAG;
    float* sq2 = sq1 + kB * kL;
    float* w1  = sq2 + kB * kL;
    float* w2  = w1 + kB * kL;
    float* xcat = w2 + kB * kL;

    hipMemsetAsync(xcat, 0, kB * 600 * sizeof(float), stream);
    wprep_kernel<<<dim3(W_FRAG / 256, 2), 256, 0, stream>>>(Ws, Wfrag);
    embprep_kernel<<<dim3(kB * kL / 16, 2), 256, 0, stream>>>(q1, q2, emb, e1, e2,
                                                              sbf1, sbf2, sq1, sq2, xcat);

    // ---- layer 0  (matchf/match_sums grids: b on x -> same-b blocks share an XCD)
    matchf_kernel<<<dim3(kB, 2, 2), 256, 0, stream>>>(sbf1, sbf2, sq1, sq2, Wfrag, fb1, fb2);
    conv_kernel<<<dim3(kL / 32, kB, 2), 256, 0, stream>>>(e1, e2, fb1, fb2, ck, cb,
                                                          o1, o2, xcat, 100, 400,
                                                          1, 1, q1, q2, sbf1, sbf2, sq1, sq2, w1, w2);
    match_sums<<<dim3(kB, 2), 256, 0, stream>>>(sbf1, sbf2, sq1, sq2, w1, w2);
    poolprep_kernel<<<dim3(kB * kL / 16, 2), 256, 0, stream>>>(o1, o2, w1, w2, q1, q2,
                                                               e1, e2, sbf1, sbf2, sq1, sq2);
    // ---- layer 1 (tail match/pool dead; o-store also dead)
    matchf_kernel<<<dim3(kB, 2, 2), 256, 0, stream>>>(sbf1, sbf2, sq1, sq2, Wfrag + W_FRAG, fb1, fb2);
    conv_kernel<<<dim3(kL / 32, kB, 2), 256, 0, stream>>>(e1, e2, fb1, fb2, ck + 18, cb + 1,
                                                          o1, o2, xcat, 200, 500,
                                                          0, 0, q1, q2, sbf1, sbf2, sq1, sq2, w1, w2);

    head_kernel<<<kB, 512, 0, stream>>>(xcat, fc1w, fc1b, lng, lnb, fc2w, fc2b, out);
}